// Round 1
// baseline (266.771 us; speedup 1.0000x reference)
//
#include <hip/hip_runtime.h>
#include <math.h>

#define NGRAPH 256
#define NPG 256
#define DEGC 16
#define HF 128
#define NTOT (NGRAPH*NPG)
#define EPG (NPG*DEGC)
#define ETOT (NTOT*DEGC)
#define TSTR 132   // padded LDS row stride (floats) for bank spread, 16B-aligned

// ---------------- CSR build: per-graph counting sort by dst ----------------
__global__ __launch_bounds__(256) void build_csr(const int* __restrict__ src,
                                                 const int* __restrict__ dst,
                                                 int* __restrict__ rowptr,
                                                 unsigned char* __restrict__ col) {
  __shared__ int cnt[NPG];
  __shared__ int scan_[NPG];
  __shared__ int cur[NPG];
  int g = blockIdx.x, tid = threadIdx.x;
  int ebase = g * EPG, nb = g * NPG;
  cnt[tid] = 0;
  __syncthreads();
  for (int e = tid; e < EPG; e += 256) atomicAdd(&cnt[dst[ebase+e] - nb], 1);
  __syncthreads();
  scan_[tid] = cnt[tid];
  __syncthreads();
  for (int off = 1; off < NPG; off <<= 1) {
    int v = (tid >= off) ? scan_[tid-off] : 0;
    __syncthreads();
    scan_[tid] += v;
    __syncthreads();
  }
  int excl = scan_[tid] - cnt[tid];
  rowptr[g*(NPG+1) + tid] = ebase + excl;
  if (tid == NPG-1) rowptr[g*(NPG+1) + NPG] = ebase + EPG;
  cur[tid] = excl;
  __syncthreads();
  for (int e = tid; e < EPG; e += 256) {
    int d = dst[ebase+e] - nb;
    int slot = atomicAdd(&cur[d], 1);
    col[ebase + slot] = (unsigned char)(src[ebase+e] - nb);
  }
}

// ---------------- f32 matmul: Y[N,128] = X[N,128] @ W[128,128] ----------------
__global__ __launch_bounds__(512) void mm_f32(const float* __restrict__ X,
                                              const float* __restrict__ W,
                                              float* __restrict__ Y) {
  __shared__ float Wl[128*128];      // 64 KB
  __shared__ float xT[128*TSTR];     // transposed tile: xT[k][r], 67.5 KB
  int tid = threadIdx.x;
  int rowbase = blockIdx.x * 128;

  const float4* W4 = (const float4*)W;
  float4* Wl4 = (float4*)Wl;
  #pragma unroll
  for (int i = 0; i < 8; ++i) Wl4[tid + i*512] = W4[tid + i*512];

  const float4* X4 = (const float4*)(X + (size_t)rowbase * HF);
  #pragma unroll
  for (int i = 0; i < 8; ++i) {
    int f4 = tid + i*512;
    int r = f4 >> 5, kq = f4 & 31;
    float4 v = X4[f4];
    xT[(kq*4+0)*TSTR + r] = v.x;
    xT[(kq*4+1)*TSTR + r] = v.y;
    xT[(kq*4+2)*TSTR + r] = v.z;
    xT[(kq*4+3)*TSTR + r] = v.w;
  }
  __syncthreads();

  int cgrp = tid & 31, rgrp = tid >> 5;
  int c0 = cgrp*4, r0 = rgrp*8;
  float acc[8][4] = {};
  #pragma unroll 4
  for (int k = 0; k < 128; ++k) {
    float4 w4 = *(const float4*)&Wl[k*128 + c0];
    float4 xa = *(const float4*)&xT[k*TSTR + r0];
    float4 xb = *(const float4*)&xT[k*TSTR + r0 + 4];
    float xs[8] = {xa.x,xa.y,xa.z,xa.w,xb.x,xb.y,xb.z,xb.w};
    #pragma unroll
    for (int rr = 0; rr < 8; ++rr) {
      acc[rr][0] += xs[rr]*w4.x;
      acc[rr][1] += xs[rr]*w4.y;
      acc[rr][2] += xs[rr]*w4.z;
      acc[rr][3] += xs[rr]*w4.w;
    }
  }
  #pragma unroll
  for (int rr = 0; rr < 8; ++rr) {
    float4 st;
    st.x = acc[rr][0]; st.y = acc[rr][1]; st.z = acc[rr][2]; st.w = acc[rr][3];
    *(float4*)&Y[(size_t)(rowbase + r0 + rr)*HF + c0] = st;
  }
}

// ---------------- fused per-graph layer: agg + relu + score + topk + scale + readout ----------------
template<bool FIRST, int K>
__global__ __launch_bounds__(1024) void layerA(
    const float* __restrict__ T,      // [N,128] pre-aggregation transform (h_prev @ W)
    const float* __restrict__ bias,   // [128]
    const float* __restrict__ Wsc,    // [128] score weights
    const float* __restrict__ bsc,    // [1]
    const int* __restrict__ rowptr,   // [B*(NPG+1)]
    const unsigned char* __restrict__ col, // [E] src local idx, sorted by dst
    unsigned char* __restrict__ mask, // [N] in/out survivor mask
    float* __restrict__ Hout,         // [N,128] scaled output features
    float* __restrict__ Z)            // [B,256] readout accumulator
{
  __shared__ float tbuf[NPG*TSTR];        // 132 KB
  __shared__ unsigned char colS[EPG];     // 4 KB
  __shared__ unsigned short rloc[NPG+2];
  __shared__ float mprev[NPG];
  __shared__ float dinv[NPG];
  __shared__ float bvec[HF];
  __shared__ float wsv[HF];
  __shared__ float tsv[NPG];
  __shared__ float score[NPG];
  __shared__ float tscale[NPG];
  __shared__ float nmf[NPG];
  __shared__ float skey[NPG];
  __shared__ int   sidx[NPG];
  __shared__ float red[8*HF];             // 4 KB

  int tid = threadIdx.x;
  int g = blockIdx.x;
  size_t nbase = (size_t)g * NPG;

  // ---- stage ----
  const float4* T4 = (const float4*)(T + nbase*HF);
  #pragma unroll
  for (int i = 0; i < 8; ++i) {
    int f4 = tid + i*1024;
    int r = f4 >> 5, kq = f4 & 31;
    *(float4*)&tbuf[r*TSTR + kq*4] = T4[f4];
  }
  ((int*)colS)[tid] = ((const int*)(col + (size_t)g*EPG))[tid];  // 1024 ints = 4096 B
  if (tid <= NPG) rloc[tid] = (unsigned short)(rowptr[g*(NPG+1)+tid] - g*EPG);
  if (tid < NPG)  mprev[tid] = FIRST ? 1.0f : (mask[nbase+tid] ? 1.0f : 0.0f);
  if (tid < HF) { bvec[tid] = bias[tid]; wsv[tid] = Wsc[tid]; }
  __syncthreads();

  // ---- degree / dinv ----
  if (tid < NPG) {
    int v = tid;
    float cf = 0.f;
    int e0 = rloc[v], e1 = rloc[v+1];
    for (int e = e0; e < e1; ++e) cf += mprev[colS[e]];
    dinv[v] = (mprev[v] > 0.f) ? (1.0f / sqrtf(cf + 1.0f)) : 0.0f;
  }
  __syncthreads();

  // ---- main aggregation into registers ----
  int v = tid >> 2, fq = tid & 3;
  int fb = fq * 32;
  float4 acc[8] = {};
  {
    float dv = dinv[v];
    if (dv > 0.f) {
      int e0 = rloc[v], e1 = rloc[v+1];
      for (int e = e0; e < e1; ++e) {
        int s = colS[e];
        float w = dinv[s];
        if (w > 0.f) {
          const float* ts = &tbuf[s*TSTR + fb];
          #pragma unroll
          for (int i = 0; i < 8; ++i) {
            float4 tv = *(const float4*)&ts[i*4];
            acc[i].x += w*tv.x; acc[i].y += w*tv.y;
            acc[i].z += w*tv.z; acc[i].w += w*tv.w;
          }
        }
      }
      const float* tv0 = &tbuf[v*TSTR + fb];
      #pragma unroll
      for (int i = 0; i < 8; ++i) {
        float4 tv = *(const float4*)&tv0[i*4];
        acc[i].x += dv*tv.x; acc[i].y += dv*tv.y;
        acc[i].z += dv*tv.z; acc[i].w += dv*tv.w;
      }
      #pragma unroll
      for (int i = 0; i < 8; ++i) {
        acc[i].x *= dv; acc[i].y *= dv; acc[i].z *= dv; acc[i].w *= dv;
      }
    }
  }
  __syncthreads();
  // h = relu(agg + b), write back in place
  #pragma unroll
  for (int i = 0; i < 8; ++i) {
    float4 a = acc[i];
    a.x = fmaxf(a.x + bvec[fb+4*i+0], 0.f);
    a.y = fmaxf(a.y + bvec[fb+4*i+1], 0.f);
    a.z = fmaxf(a.z + bvec[fb+4*i+2], 0.f);
    a.w = fmaxf(a.w + bvec[fb+4*i+3], 0.f);
    *(float4*)&tbuf[v*TSTR + fb + 4*i] = a;
  }
  __syncthreads();

  // ---- score pre-transform: tsv[v] = h[v] . Ws  (one wave per 16 nodes) ----
  {
    int wid = tid >> 6, lane = tid & 63;
    for (int j = 0; j < 16; ++j) {
      int vv = wid*16 + j;
      float p = tbuf[vv*TSTR + lane]*wsv[lane] + tbuf[vv*TSTR + 64 + lane]*wsv[64+lane];
      #pragma unroll
      for (int o = 32; o > 0; o >>= 1) p += __shfl_xor(p, o);
      if (lane == 0) tsv[vv] = p;
    }
  }
  __syncthreads();

  // ---- score aggregation + sort init ----
  if (tid < NPG) {
    int vv = tid;
    float dv = dinv[vv];
    float sa = 0.f;
    if (dv > 0.f) {
      int e0 = rloc[vv], e1 = rloc[vv+1];
      for (int e = e0; e < e1; ++e) { int s = colS[e]; sa += tsv[s]*dinv[s]; }
      sa = dv*(sa + dv*tsv[vv]);
    }
    float sc = sa + bsc[0];
    score[vv] = sc;
    skey[vv] = (mprev[vv] > 0.f) ? sc : -INFINITY;
    sidx[vv] = vv;
    nmf[vv] = 0.f;
  }

  // ---- bitonic sort, descending score, ascending index on ties ----
  for (int kk = 2; kk <= NPG; kk <<= 1) {
    for (int j = kk >> 1; j > 0; j >>= 1) {
      __syncthreads();
      if (tid < NPG) {
        int i = tid, l = i ^ j;
        if (l > i) {
          float s1 = skey[i], s2 = skey[l];
          int i1 = sidx[i], i2 = sidx[l];
          bool g12 = (s1 > s2) || (s1 == s2 && i1 < i2);   // entry i ranks before l
          bool descRegion = ((i & kk) == 0);
          bool doswap = descRegion ? (!g12) : g12;
          if (doswap) { skey[i] = s2; skey[l] = s1; sidx[i] = i2; sidx[l] = i1; }
        }
      }
    }
  }
  __syncthreads();
  if (tid < K) nmf[sidx[tid]] = 1.0f;
  __syncthreads();
  if (tid < NPG) {
    tscale[tid] = tanhf(score[tid]) * nmf[tid];
    mask[nbase + tid] = (unsigned char)(nmf[tid] > 0.f ? 1 : 0);
  }
  __syncthreads();

  // ---- scale features in place ----
  {
    float tsc = tscale[v];
    #pragma unroll
    for (int i = 0; i < 8; ++i) {
      float4 t = *(float4*)&tbuf[v*TSTR + fb + 4*i];
      t.x *= tsc; t.y *= tsc; t.z *= tsc; t.w *= tsc;
      *(float4*)&tbuf[v*TSTR + fb + 4*i] = t;
    }
  }
  __syncthreads();

  // ---- coalesced copy to global ----
  float4* H4 = (float4*)(Hout + nbase*HF);
  #pragma unroll
  for (int i = 0; i < 8; ++i) {
    int f4 = tid + i*1024;
    int r = f4 >> 5, kq = f4 & 31;
    H4[f4] = *(float4*)&tbuf[r*TSTR + kq*4];
  }

  // ---- readout: max & mean over selected nodes ----
  int f = tid & 127, vg = tid >> 7;
  float mx = -INFINITY, sm = 0.f;
  for (int vr = 0; vr < 32; ++vr) {
    int vv = vg*32 + vr;
    float val = tbuf[vv*TSTR + f];
    if (nmf[vv] > 0.f) { mx = fmaxf(mx, val); sm += val; }
  }
  red[vg*HF + f] = mx;
  __syncthreads();
  float zmax = 0.f;
  if (tid < HF) {
    zmax = red[tid];
    #pragma unroll
    for (int q = 1; q < 8; ++q) zmax = fmaxf(zmax, red[q*HF + tid]);
  }
  __syncthreads();
  red[vg*HF + f] = sm;
  __syncthreads();
  if (tid < HF) {
    float zsum = red[tid];
    #pragma unroll
    for (int q = 1; q < 8; ++q) zsum += red[q*HF + tid];
    float* zp = Z + (size_t)g*256;
    float mn = zsum / (float)K;
    if (FIRST) { zp[tid] = zmax; zp[HF + tid] = mn; }
    else       { zp[tid] += zmax; zp[HF + tid] += mn; }
  }
}

// ---------------- MLP head + log_softmax ----------------
__global__ __launch_bounds__(128) void mlp_head(const float* __restrict__ Z,
    const float* __restrict__ Wl1, const float* __restrict__ bl1,
    const float* __restrict__ Wl2, const float* __restrict__ bl2,
    const float* __restrict__ Wl3, const float* __restrict__ bl3,
    float* __restrict__ out) {
  __shared__ float zr[256];
  __shared__ float h1[128];
  __shared__ float h2[64];
  __shared__ float lg[10];
  __shared__ float mred[2];
  int g = blockIdx.x, tid = threadIdx.x;
  zr[tid] = Z[(size_t)g*256 + tid];
  zr[128 + tid] = Z[(size_t)g*256 + 128 + tid];
  __syncthreads();
  {
    float a = bl1[tid];
    for (int k = 0; k < 256; ++k) a += zr[k]*Wl1[k*128 + tid];
    h1[tid] = fmaxf(a, 0.f);
  }
  __syncthreads();
  if (tid < 64) {
    float a = bl2[tid];
    for (int k = 0; k < 128; ++k) a += h1[k]*Wl2[k*64 + tid];
    h2[tid] = fmaxf(a, 0.f);
  }
  __syncthreads();
  if (tid < 10) {
    float a = bl3[tid];
    for (int k = 0; k < 64; ++k) a += h2[k]*Wl3[k*10 + tid];
    lg[tid] = fmaxf(a, 0.f);
  }
  __syncthreads();
  if (tid == 0) {
    float m = lg[0];
    for (int i = 1; i < 10; ++i) m = fmaxf(m, lg[i]);
    float s = 0.f;
    for (int i = 0; i < 10; ++i) s += expf(lg[i] - m);
    mred[0] = m; mred[1] = logf(s);
  }
  __syncthreads();
  if (tid < 10) out[(size_t)g*10 + tid] = lg[tid] - mred[0] - mred[1];
}

extern "C" void kernel_launch(void* const* d_in, const int* in_sizes, int n_in,
                              void* d_out, int out_size, void* d_ws, size_t ws_size,
                              hipStream_t stream) {
  const float* x   = (const float*)d_in[0];
  const int*  srcI = (const int*)d_in[1];
  const int*  dstI = (const int*)d_in[2];
  const float* W1  = (const float*)d_in[3];
  const float* b1  = (const float*)d_in[4];
  const float* W2  = (const float*)d_in[5];
  const float* b2  = (const float*)d_in[6];
  const float* W3  = (const float*)d_in[7];
  const float* b3  = (const float*)d_in[8];
  const float* Ws1 = (const float*)d_in[9];
  const float* bs1 = (const float*)d_in[10];
  const float* Ws2 = (const float*)d_in[11];
  const float* bs2 = (const float*)d_in[12];
  const float* Ws3 = (const float*)d_in[13];
  const float* bs3 = (const float*)d_in[14];
  const float* Wl1 = (const float*)d_in[15];
  const float* bl1 = (const float*)d_in[16];
  const float* Wl2 = (const float*)d_in[17];
  const float* bl2 = (const float*)d_in[18];
  const float* Wl3 = (const float*)d_in[19];
  const float* bl3 = (const float*)d_in[20];
  float* out = (float*)d_out;

  // workspace layout
  char* ws = (char*)d_ws;
  float* bufT = (float*)ws;                          ws += (size_t)NTOT*HF*sizeof(float);
  float* bufH = (float*)ws;                          ws += (size_t)NTOT*HF*sizeof(float);
  float* zbuf = (float*)ws;                          ws += (size_t)NGRAPH*256*sizeof(float);
  int* rowptr = (int*)ws;                            ws += (size_t)NGRAPH*(NPG+1)*sizeof(int);
  unsigned char* colb = (unsigned char*)ws;          ws += (size_t)ETOT;
  unsigned char* maskb = (unsigned char*)ws;         ws += (size_t)NTOT;

  build_csr<<<NGRAPH, 256, 0, stream>>>(srcI, dstI, rowptr, colb);

  // layer 1
  mm_f32<<<NTOT/128, 512, 0, stream>>>(x, W1, bufT);
  layerA<true, 128><<<NGRAPH, 1024, 0, stream>>>(bufT, b1, Ws1, bs1, rowptr, colb, maskb, bufH, zbuf);
  // layer 2
  mm_f32<<<NTOT/128, 512, 0, stream>>>(bufH, W2, bufT);
  layerA<false, 64><<<NGRAPH, 1024, 0, stream>>>(bufT, b2, Ws2, bs2, rowptr, colb, maskb, bufH, zbuf);
  // layer 3
  mm_f32<<<NTOT/128, 512, 0, stream>>>(bufH, W3, bufT);
  layerA<false, 32><<<NGRAPH, 1024, 0, stream>>>(bufT, b3, Ws3, bs3, rowptr, colb, maskb, bufH, zbuf);

  mlp_head<<<NGRAPH, 128, 0, stream>>>(zbuf, Wl1, bl1, Wl2, bl2, Wl3, bl3, out);
}

// Round 2
// 265.467 us; speedup vs baseline: 1.0049x; 1.0049x over previous
//
#include <hip/hip_runtime.h>
#include <math.h>

#define NGRAPH 256
#define NPG 256
#define DEGC 16
#define HF 128
#define NTOT (NGRAPH*NPG)
#define EPG (NPG*DEGC)
#define ETOT (NTOT*DEGC)
#define TSTR 132   // padded LDS row stride (floats)

typedef __attribute__((ext_vector_type(8))) short bf16x8;
typedef __attribute__((ext_vector_type(4))) float f32x4;

__device__ inline unsigned short f2bf(float f) {
  unsigned u = __builtin_bit_cast(unsigned, f);
  unsigned r = (u + 0x7FFFu + ((u >> 16) & 1u)) >> 16;
  return (unsigned short)r;
}
__device__ inline float bf2f(unsigned short h) {
  unsigned u = ((unsigned)h) << 16;
  return __builtin_bit_cast(float, u);
}

// ---------------- CSR build: per-graph counting sort by dst ----------------
__global__ __launch_bounds__(256) void build_csr(const int* __restrict__ src,
                                                 const int* __restrict__ dst,
                                                 int* __restrict__ rowptr,
                                                 unsigned char* __restrict__ col) {
  __shared__ int cnt[NPG];
  __shared__ int scan_[NPG];
  __shared__ int cur[NPG];
  int g = blockIdx.x, tid = threadIdx.x;
  int ebase = g * EPG, nb = g * NPG;
  cnt[tid] = 0;
  __syncthreads();
  for (int e = tid; e < EPG; e += 256) atomicAdd(&cnt[dst[ebase+e] - nb], 1);
  __syncthreads();
  scan_[tid] = cnt[tid];
  __syncthreads();
  for (int off = 1; off < NPG; off <<= 1) {
    int v = (tid >= off) ? scan_[tid-off] : 0;
    __syncthreads();
    scan_[tid] += v;
    __syncthreads();
  }
  int excl = scan_[tid] - cnt[tid];
  rowptr[g*(NPG+1) + tid] = ebase + excl;
  if (tid == NPG-1) rowptr[g*(NPG+1) + NPG] = ebase + EPG;
  cur[tid] = excl;
  __syncthreads();
  for (int e = tid; e < EPG; e += 256) {
    int d = dst[ebase+e] - nb;
    int slot = atomicAdd(&cur[d], 1);
    col[ebase + slot] = (unsigned char)(src[ebase+e] - nb);
  }
}

// ---------------- W transpose + split to bf16 hi/lo: Wt[n][k] ----------------
__global__ __launch_bounds__(256) void prep_wt(const float* __restrict__ W1,
                                               const float* __restrict__ W2,
                                               const float* __restrict__ W3,
                                               short* __restrict__ Wt) {
  int idx = blockIdx.x * 256 + threadIdx.x;           // 0 .. 3*16384
  int L = idx >> 14, r = idx & 16383;
  int k = r >> 7, n = r & 127;
  const float* W = (L == 0) ? W1 : (L == 1) ? W2 : W3;
  float w = W[k*128 + n];
  unsigned short hi = f2bf(w);
  unsigned short lo = f2bf(w - bf2f(hi));
  short* Whi = Wt + (size_t)L * 2 * 16384;
  short* Wlo = Whi + 16384;
  Whi[n*128 + k] = (short)hi;
  Wlo[n*128 + k] = (short)lo;
}

// ---------------- split-bf16 MFMA matmul: Y[N,128] = X[N,128] @ W ----------------
// Wt is [n][k] bf16 (hi then lo). Per wave: 16 rows x 128 cols.
__global__ __launch_bounds__(256) void mm_mfma(const float* __restrict__ X,
                                               const short* __restrict__ Wt,
                                               float* __restrict__ Y) {
  int tid = threadIdx.x;
  int wid = tid >> 6, lane = tid & 63;
  int rowbase = blockIdx.x * 64 + wid * 16;
  int lr = lane & 15;            // row within 16-tile (A) / col within tile (B)
  int lk = (lane >> 4) * 8;      // k offset within 32-chunk
  const short* Whi = Wt;
  const short* Wlo = Wt + 16384;

  f32x4 acc[8] = {};
  #pragma unroll
  for (int kc = 0; kc < 4; ++kc) {
    int k0 = kc*32 + lk;
    bf16x8 bh[8], bl[8];
    #pragma unroll
    for (int ct = 0; ct < 8; ++ct) {
      int n = ct*16 + lr;
      bh[ct] = *(const bf16x8*)&Whi[n*128 + k0];
      bl[ct] = *(const bf16x8*)&Wlo[n*128 + k0];
    }
    const float* xp = &X[(size_t)(rowbase + lr)*HF + k0];
    float xa[8];
    *(float4*)&xa[0] = *(const float4*)xp;
    *(float4*)&xa[4] = *(const float4*)(xp + 4);
    bf16x8 ah, al;
    #pragma unroll
    for (int j = 0; j < 8; ++j) {
      unsigned short h = f2bf(xa[j]);
      ah[j] = (short)h;
      al[j] = (short)f2bf(xa[j] - bf2f(h));
    }
    #pragma unroll
    for (int ct = 0; ct < 8; ++ct) {
      acc[ct] = __builtin_amdgcn_mfma_f32_16x16x32_bf16(ah, bh[ct], acc[ct], 0, 0, 0);
      acc[ct] = __builtin_amdgcn_mfma_f32_16x16x32_bf16(ah, bl[ct], acc[ct], 0, 0, 0);
      acc[ct] = __builtin_amdgcn_mfma_f32_16x16x32_bf16(al, bh[ct], acc[ct], 0, 0, 0);
    }
  }
  // C/D: col = lane&15, row = (lane>>4)*4 + j   [m89-verified]
  int orow = rowbase + (lane >> 4) * 4;
  #pragma unroll
  for (int ct = 0; ct < 8; ++ct) {
    #pragma unroll
    for (int j = 0; j < 4; ++j) {
      Y[(size_t)(orow + j)*HF + ct*16 + lr] = acc[ct][j];
    }
  }
}

// ---------------- fused per-graph layer: agg + relu + score + topk + scale + readout ----------------
template<bool FIRST, int K>
__global__ __launch_bounds__(1024) void layerA(
    const float* __restrict__ T,      // [N,128] pre-aggregation transform (h_prev @ W)
    const float* __restrict__ bias,   // [128]
    const float* __restrict__ Wsc,    // [128] score weights
    const float* __restrict__ bsc,    // [1]
    const int* __restrict__ rowptr,   // [B*(NPG+1)]
    const unsigned char* __restrict__ col, // [E] src local idx, sorted by dst
    unsigned char* __restrict__ mask, // [N] in/out survivor mask
    float* __restrict__ Hout,         // [N,128] scaled output features
    float* __restrict__ Z)            // [B,256] readout accumulator
{
  __shared__ float tbuf[NPG*TSTR];        // 132 KB
  __shared__ unsigned char colS[EPG];     // 4 KB
  __shared__ unsigned short rloc[NPG+2];
  __shared__ float mprev[NPG];
  __shared__ float dinv[NPG];
  __shared__ float bvec[HF];
  __shared__ float wsv[HF];
  __shared__ float tsv[NPG];
  __shared__ float score[NPG];
  __shared__ float tscale[NPG];
  __shared__ float nmf[NPG];
  __shared__ float skey[NPG];
  __shared__ int   sidx[NPG];
  __shared__ float red[8*HF];             // 4 KB

  int tid = threadIdx.x;
  int g = blockIdx.x;
  size_t nbase = (size_t)g * NPG;

  // ---- stage ----
  const float4* T4 = (const float4*)(T + nbase*HF);
  #pragma unroll
  for (int i = 0; i < 8; ++i) {
    int f4 = tid + i*1024;
    int r = f4 >> 5, kq = f4 & 31;
    *(float4*)&tbuf[r*TSTR + kq*4] = T4[f4];
  }
  ((int*)colS)[tid] = ((const int*)(col + (size_t)g*EPG))[tid];
  if (tid <= NPG) rloc[tid] = (unsigned short)(rowptr[g*(NPG+1)+tid] - g*EPG);
  if (tid < NPG)  mprev[tid] = FIRST ? 1.0f : (mask[nbase+tid] ? 1.0f : 0.0f);
  if (tid < HF) { bvec[tid] = bias[tid]; wsv[tid] = Wsc[tid]; }
  __syncthreads();

  // ---- degree / dinv ----
  if (tid < NPG) {
    int vv = tid;
    float cf = 0.f;
    int e0 = rloc[vv], e1 = rloc[vv+1];
    for (int e = e0; e < e1; ++e) cf += mprev[colS[e]];
    dinv[vv] = (mprev[vv] > 0.f) ? (1.0f / sqrtf(cf + 1.0f)) : 0.0f;
  }
  __syncthreads();

  // ---- main aggregation into registers ----
  // thread (v, fq) owns columns {16*i + 4*fq + c} -> fq lanes hit disjoint banks
  int v = tid >> 2, fq = tid & 3;
  int cb = fq * 4;
  float4 acc[8] = {};
  {
    float dv = dinv[v];
    if (dv > 0.f) {
      int e0 = rloc[v], e1 = rloc[v+1];
      for (int e = e0; e < e1; ++e) {
        int s = colS[e];
        float w = dinv[s];
        if (w > 0.f) {
          const float* ts = &tbuf[s*TSTR + cb];
          #pragma unroll
          for (int i = 0; i < 8; ++i) {
            float4 tv = *(const float4*)&ts[i*16];
            acc[i].x += w*tv.x; acc[i].y += w*tv.y;
            acc[i].z += w*tv.z; acc[i].w += w*tv.w;
          }
        }
      }
      const float* tv0 = &tbuf[v*TSTR + cb];
      #pragma unroll
      for (int i = 0; i < 8; ++i) {
        float4 tv = *(const float4*)&tv0[i*16];
        acc[i].x += dv*tv.x; acc[i].y += dv*tv.y;
        acc[i].z += dv*tv.z; acc[i].w += dv*tv.w;
      }
      #pragma unroll
      for (int i = 0; i < 8; ++i) {
        acc[i].x *= dv; acc[i].y *= dv; acc[i].z *= dv; acc[i].w *= dv;
      }
    }
  }
  __syncthreads();
  // h = relu(agg + b), write back in place
  #pragma unroll
  for (int i = 0; i < 8; ++i) {
    int ci = i*16 + cb;
    float4 a = acc[i];
    a.x = fmaxf(a.x + bvec[ci+0], 0.f);
    a.y = fmaxf(a.y + bvec[ci+1], 0.f);
    a.z = fmaxf(a.z + bvec[ci+2], 0.f);
    a.w = fmaxf(a.w + bvec[ci+3], 0.f);
    *(float4*)&tbuf[v*TSTR + ci] = a;
  }
  __syncthreads();

  // ---- score pre-transform: tsv[v] = h[v] . Ws ----
  {
    int wid = tid >> 6, lane = tid & 63;
    for (int j = 0; j < 16; ++j) {
      int vv = wid*16 + j;
      float p = tbuf[vv*TSTR + lane]*wsv[lane] + tbuf[vv*TSTR + 64 + lane]*wsv[64+lane];
      #pragma unroll
      for (int o = 32; o > 0; o >>= 1) p += __shfl_xor(p, o);
      if (lane == 0) tsv[vv] = p;
    }
  }
  __syncthreads();

  // ---- score aggregation + sort init ----
  if (tid < NPG) {
    int vv = tid;
    float dv = dinv[vv];
    float sa = 0.f;
    if (dv > 0.f) {
      int e0 = rloc[vv], e1 = rloc[vv+1];
      for (int e = e0; e < e1; ++e) { int s = colS[e]; sa += tsv[s]*dinv[s]; }
      sa = dv*(sa + dv*tsv[vv]);
    }
    float sc = sa + bsc[0];
    score[vv] = sc;
    skey[vv] = (mprev[vv] > 0.f) ? sc : -INFINITY;
    sidx[vv] = vv;
    nmf[vv] = 0.f;
  }

  // ---- bitonic sort, descending score, ascending index on ties ----
  for (int kk = 2; kk <= NPG; kk <<= 1) {
    for (int j = kk >> 1; j > 0; j >>= 1) {
      __syncthreads();
      if (tid < NPG) {
        int i = tid, l = i ^ j;
        if (l > i) {
          float s1 = skey[i], s2 = skey[l];
          int i1 = sidx[i], i2 = sidx[l];
          bool g12 = (s1 > s2) || (s1 == s2 && i1 < i2);
          bool descRegion = ((i & kk) == 0);
          bool doswap = descRegion ? (!g12) : g12;
          if (doswap) { skey[i] = s2; skey[l] = s1; sidx[i] = i2; sidx[l] = i1; }
        }
      }
    }
  }
  __syncthreads();
  if (tid < K) nmf[sidx[tid]] = 1.0f;
  __syncthreads();
  if (tid < NPG) {
    tscale[tid] = tanhf(score[tid]) * nmf[tid];
    mask[nbase + tid] = (unsigned char)(nmf[tid] > 0.f ? 1 : 0);
  }
  __syncthreads();

  // ---- scale features in place ----
  {
    float tsc = tscale[v];
    #pragma unroll
    for (int i = 0; i < 8; ++i) {
      int ci = i*16 + cb;
      float4 t = *(float4*)&tbuf[v*TSTR + ci];
      t.x *= tsc; t.y *= tsc; t.z *= tsc; t.w *= tsc;
      *(float4*)&tbuf[v*TSTR + ci] = t;
    }
  }
  __syncthreads();

  // ---- coalesced copy to global ----
  float4* H4 = (float4*)(Hout + nbase*HF);
  #pragma unroll
  for (int i = 0; i < 8; ++i) {
    int f4 = tid + i*1024;
    int r = f4 >> 5, kq = f4 & 31;
    H4[f4] = *(float4*)&tbuf[r*TSTR + kq*4];
  }

  // ---- readout: max & mean over selected nodes ----
  int f = tid & 127, vg = tid >> 7;
  float mx = -INFINITY, sm = 0.f;
  for (int vr = 0; vr < 32; ++vr) {
    int vv = vg*32 + vr;
    float val = tbuf[vv*TSTR + f];
    if (nmf[vv] > 0.f) { mx = fmaxf(mx, val); sm += val; }
  }
  red[vg*HF + f] = mx;
  __syncthreads();
  float zmax = 0.f;
  if (tid < HF) {
    zmax = red[tid];
    #pragma unroll
    for (int q = 1; q < 8; ++q) zmax = fmaxf(zmax, red[q*HF + tid]);
  }
  __syncthreads();
  red[vg*HF + f] = sm;
  __syncthreads();
  if (tid < HF) {
    float zsum = red[tid];
    #pragma unroll
    for (int q = 1; q < 8; ++q) zsum += red[q*HF + tid];
    float* zp = Z + (size_t)g*256;
    float mn = zsum / (float)K;
    if (FIRST) { zp[tid] = zmax; zp[HF + tid] = mn; }
    else       { zp[tid] += zmax; zp[HF + tid] += mn; }
  }
}

// ---------------- MLP head + log_softmax ----------------
__global__ __launch_bounds__(128) void mlp_head(const float* __restrict__ Z,
    const float* __restrict__ Wl1, const float* __restrict__ bl1,
    const float* __restrict__ Wl2, const float* __restrict__ bl2,
    const float* __restrict__ Wl3, const float* __restrict__ bl3,
    float* __restrict__ out) {
  __shared__ float zr[256];
  __shared__ float h1[128];
  __shared__ float h2[64];
  __shared__ float lg[10];
  __shared__ float mred[2];
  int g = blockIdx.x, tid = threadIdx.x;
  zr[tid] = Z[(size_t)g*256 + tid];
  zr[128 + tid] = Z[(size_t)g*256 + 128 + tid];
  __syncthreads();
  {
    float a = bl1[tid];
    for (int k = 0; k < 256; ++k) a += zr[k]*Wl1[k*128 + tid];
    h1[tid] = fmaxf(a, 0.f);
  }
  __syncthreads();
  if (tid < 64) {
    float a = bl2[tid];
    for (int k = 0; k < 128; ++k) a += h1[k]*Wl2[k*64 + tid];
    h2[tid] = fmaxf(a, 0.f);
  }
  __syncthreads();
  if (tid < 10) {
    float a = bl3[tid];
    for (int k = 0; k < 64; ++k) a += h2[k]*Wl3[k*10 + tid];
    lg[tid] = fmaxf(a, 0.f);
  }
  __syncthreads();
  if (tid == 0) {
    float m = lg[0];
    for (int i = 1; i < 10; ++i) m = fmaxf(m, lg[i]);
    float s = 0.f;
    for (int i = 0; i < 10; ++i) s += expf(lg[i] - m);
    mred[0] = m; mred[1] = logf(s);
  }
  __syncthreads();
  if (tid < 10) out[(size_t)g*10 + tid] = lg[tid] - mred[0] - mred[1];
}

extern "C" void kernel_launch(void* const* d_in, const int* in_sizes, int n_in,
                              void* d_out, int out_size, void* d_ws, size_t ws_size,
                              hipStream_t stream) {
  const float* x   = (const float*)d_in[0];
  const int*  srcI = (const int*)d_in[1];
  const int*  dstI = (const int*)d_in[2];
  const float* W1  = (const float*)d_in[3];
  const float* b1  = (const float*)d_in[4];
  const float* W2  = (const float*)d_in[5];
  const float* b2  = (const float*)d_in[6];
  const float* W3  = (const float*)d_in[7];
  const float* b3  = (const float*)d_in[8];
  const float* Ws1 = (const float*)d_in[9];
  const float* bs1 = (const float*)d_in[10];
  const float* Ws2 = (const float*)d_in[11];
  const float* bs2 = (const float*)d_in[12];
  const float* Ws3 = (const float*)d_in[13];
  const float* bs3 = (const float*)d_in[14];
  const float* Wl1 = (const float*)d_in[15];
  const float* bl1 = (const float*)d_in[16];
  const float* Wl2 = (const float*)d_in[17];
  const float* bl2 = (const float*)d_in[18];
  const float* Wl3 = (const float*)d_in[19];
  const float* bl3 = (const float*)d_in[20];
  float* out = (float*)d_out;

  // workspace layout
  char* ws = (char*)d_ws;
  float* bufT = (float*)ws;                          ws += (size_t)NTOT*HF*sizeof(float);
  float* bufH = (float*)ws;                          ws += (size_t)NTOT*HF*sizeof(float);
  float* zbuf = (float*)ws;                          ws += (size_t)NGRAPH*256*sizeof(float);
  int* rowptr = (int*)ws;                            ws += (size_t)NGRAPH*(NPG+1)*sizeof(int);
  unsigned char* colb = (unsigned char*)ws;          ws += (size_t)ETOT;
  unsigned char* maskb = (unsigned char*)ws;         ws += (size_t)NTOT;
  ws = (char*)(((size_t)ws + 255) & ~(size_t)255);
  short* WtAll = (short*)ws;                         ws += (size_t)3*2*16384*sizeof(short);

  build_csr<<<NGRAPH, 256, 0, stream>>>(srcI, dstI, rowptr, colb);
  prep_wt<<<192, 256, 0, stream>>>(W1, W2, W3, WtAll);

  // layer 1
  mm_mfma<<<NTOT/64, 256, 0, stream>>>(x, WtAll + 0*2*16384, bufT);
  layerA<true, 128><<<NGRAPH, 1024, 0, stream>>>(bufT, b1, Ws1, bs1, rowptr, colb, maskb, bufH, zbuf);
  // layer 2
  mm_mfma<<<NTOT/64, 256, 0, stream>>>(bufH, WtAll + 1*2*16384, bufT);
  layerA<false, 64><<<NGRAPH, 1024, 0, stream>>>(bufT, b2, Ws2, bs2, rowptr, colb, maskb, bufH, zbuf);
  // layer 3
  mm_mfma<<<NTOT/64, 256, 0, stream>>>(bufH, WtAll + 2*2*16384, bufT);
  layerA<false, 32><<<NGRAPH, 1024, 0, stream>>>(bufT, b3, Ws3, bs3, rowptr, colb, maskb, bufH, zbuf);

  mlp_head<<<NGRAPH, 128, 0, stream>>>(zbuf, Wl1, bl1, Wl2, bl2, Wl3, bl3, out);
}

// Round 3
// 156.846 us; speedup vs baseline: 1.7008x; 1.6925x over previous
//
#include <hip/hip_runtime.h>
#include <math.h>

#define NGRAPH 256
#define NPG 256
#define HF 128
#define EPG 4096
#define TSTR 132   // padded LDS row stride (floats)

typedef __attribute__((ext_vector_type(8))) short bf16x8;
typedef __attribute__((ext_vector_type(4))) float f32x4;

__device__ __forceinline__ unsigned short f2bf(float f) {
  unsigned u = __builtin_bit_cast(unsigned, f);
  unsigned r = (u + 0x7FFFu + ((u >> 16) & 1u)) >> 16;
  return (unsigned short)r;
}
__device__ __forceinline__ float bf2f(unsigned short h) {
  unsigned u = ((unsigned)h) << 16;
  return __builtin_bit_cast(float, u);
}

// ---------------- W transpose + split to bf16 hi/lo: Wt[n][k] ----------------
__global__ __launch_bounds__(256) void prep_wt(const float* __restrict__ W1,
                                               const float* __restrict__ W2,
                                               const float* __restrict__ W3,
                                               short* __restrict__ Wt) {
  int idx = blockIdx.x * 256 + threadIdx.x;           // 0 .. 3*16384
  int L = idx >> 14, r = idx & 16383;
  int k = r >> 7, n = r & 127;
  const float* W = (L == 0) ? W1 : (L == 1) ? W2 : W3;
  float w = W[k*128 + n];
  unsigned short hi = f2bf(w);
  unsigned short lo = f2bf(w - bf2f(hi));
  short* Whi = Wt + (size_t)L * 2 * 16384;
  short* Wlo = Whi + 16384;
  Whi[n*128 + k] = (short)hi;
  Wlo[n*128 + k] = (short)lo;
}

// sort compare-exchange step (descending key, ascending idx on ties)
#define BSTEP(OK, OI, KKc, Jc) do { \
  bool iLess = ((tid & (Jc)) == 0); \
  bool descR = ((tid & (KKc)) == 0); \
  bool myFirst = (kf > (OK)) || (kf == (OK) && ki < (OI)); \
  bool keep = (iLess == descR) ? myFirst : !myFirst; \
  if (!keep) { kf = (OK); ki = (OI); } \
} while (0)

// ---------------- whole network, one block per graph ----------------
__global__ __launch_bounds__(1024) void fused_net(
    const float* __restrict__ x,
    const int* __restrict__ srcI, const int* __restrict__ dstI,
    const short* __restrict__ WtAll,
    const float* __restrict__ b1, const float* __restrict__ Ws1, const float* __restrict__ bs1,
    const float* __restrict__ b2, const float* __restrict__ Ws2, const float* __restrict__ bs2,
    const float* __restrict__ b3, const float* __restrict__ Ws3, const float* __restrict__ bs3,
    const float* __restrict__ Wl1, const float* __restrict__ bl1,
    const float* __restrict__ Wl2, const float* __restrict__ bl2,
    const float* __restrict__ Wl3, const float* __restrict__ bl3,
    float* __restrict__ out)
{
  __shared__ float tbuf[NPG*TSTR];        // 132 KB: h / T, resident all layers
  __shared__ unsigned char colS[EPG];     // CSR col (src local idx), by dst
  __shared__ unsigned short rloc[NPG+1];
  __shared__ float mprev[NPG];
  __shared__ float dinv[NPG];
  __shared__ float bvec[HF];
  __shared__ float wsv[HF];
  __shared__ float tsv[NPG];
  __shared__ float score[NPG];
  __shared__ float tscale[NPG];
  __shared__ float nmf[NPG];
  __shared__ float skey[NPG];
  __shared__ int   sidx[NPG];
  __shared__ float red[8*HF];             // 4 KB scratch
  __shared__ float zacc[2*HF];            // readout accumulator
  __shared__ int   cntA[NPG];
  __shared__ int   curA[NPG];

  int tid = threadIdx.x;
  int g = blockIdx.x;
  size_t nbase = (size_t)g * NPG;
  int lane = tid & 63, wid = tid >> 6;

  // ---- stage x into tbuf ----
  const float4* X4 = (const float4*)(x + nbase*HF);
  #pragma unroll
  for (int i = 0; i < 8; ++i) {
    int f4 = tid + i*1024;
    int r = f4 >> 5, kq = f4 & 31;
    *(float4*)&tbuf[r*TSTR + kq*4] = X4[f4];
  }

  // ---- CSR build in LDS ----
  if (tid < NPG) cntA[tid] = 0;
  __syncthreads();
  int nb = g * NPG;
  int dloc[4], sloc[4];
  #pragma unroll
  for (int it = 0; it < 4; ++it) {
    int e = g*EPG + tid + it*1024;
    dloc[it] = dstI[e] - nb;
    sloc[it] = srcI[e] - nb;
    atomicAdd(&cntA[dloc[it]], 1);
  }
  __syncthreads();
  if (tid < NPG) sidx[tid] = cntA[tid];
  __syncthreads();
  for (int off = 1; off < NPG; off <<= 1) {
    int v = (tid >= off && tid < NPG) ? sidx[tid-off] : 0;
    __syncthreads();
    if (tid < NPG) sidx[tid] += v;
    __syncthreads();
  }
  if (tid < NPG) {
    int excl = sidx[tid] - cntA[tid];
    rloc[tid] = (unsigned short)excl;
    curA[tid] = excl;
    mprev[tid] = 1.0f;
  }
  if (tid == 0) rloc[NPG] = (unsigned short)EPG;
  __syncthreads();
  #pragma unroll
  for (int it = 0; it < 4; ++it) {
    int slot = atomicAdd(&curA[dloc[it]], 1);
    colS[slot] = (unsigned char)sloc[it];
  }
  __syncthreads();

  // ---- 3 GCN+SAGPool layers ----
  #pragma unroll 1
  for (int L = 0; L < 3; ++L) {
    const short* Whi = WtAll + (size_t)L * 2 * 16384;
    const short* Wlo = Whi + 16384;
    const float* bias = (L == 0) ? b1 : (L == 1) ? b2 : b3;
    const float* Wsc  = (L == 0) ? Ws1 : (L == 1) ? Ws2 : Ws3;
    const float* bscp = (L == 0) ? bs1 : (L == 1) ? bs2 : bs3;
    int K = NPG >> (L + 1);          // 128, 64, 32
    bool first = (L == 0);

    // params + dinv (reads mprev/colS, not tbuf)
    if (tid < HF) { bvec[tid] = bias[tid]; wsv[tid] = Wsc[tid]; }
    if (tid < NPG) {
      float cf = 0.f;
      int e0 = rloc[tid], e1 = rloc[tid+1];
      for (int e = e0; e < e1; ++e) cf += mprev[colS[e]];
      dinv[tid] = (mprev[tid] > 0.f) ? (1.0f / sqrtf(cf + 1.0f)) : 0.0f;
    }
    __syncthreads();

    // ---- transform T = h @ W (split bf16, MFMA, in place) ----
    // 16 waves = 8 row-groups x 2 col-groups; wave: 32 rows x 64 cols
    {
      int rg = wid & 7, cg = wid >> 3;
      int lr = lane & 15, lk8 = (lane >> 4) * 8;
      f32x4 tacc[2][4] = {};
      #pragma unroll
      for (int kc = 0; kc < 4; ++kc) {
        int k0 = kc*32 + lk8;
        bf16x8 ah[2], al[2];
        #pragma unroll
        for (int rt = 0; rt < 2; ++rt) {
          int row = rg*32 + rt*16 + lr;
          float xa[8];
          *(float4*)&xa[0] = *(const float4*)&tbuf[row*TSTR + k0];
          *(float4*)&xa[4] = *(const float4*)&tbuf[row*TSTR + k0 + 4];
          #pragma unroll
          for (int j = 0; j < 8; ++j) {
            unsigned short h = f2bf(xa[j]);
            ah[rt][j] = (short)h;
            al[rt][j] = (short)f2bf(xa[j] - bf2f(h));
          }
        }
        #pragma unroll
        for (int ct = 0; ct < 4; ++ct) {
          int n = cg*64 + ct*16 + lr;
          bf16x8 bh = *(const bf16x8*)&Whi[n*HF + k0];
          bf16x8 bl = *(const bf16x8*)&Wlo[n*HF + k0];
          #pragma unroll
          for (int rt = 0; rt < 2; ++rt) {
            tacc[rt][ct] = __builtin_amdgcn_mfma_f32_16x16x32_bf16(ah[rt], bh, tacc[rt][ct], 0, 0, 0);
            tacc[rt][ct] = __builtin_amdgcn_mfma_f32_16x16x32_bf16(ah[rt], bl, tacc[rt][ct], 0, 0, 0);
            tacc[rt][ct] = __builtin_amdgcn_mfma_f32_16x16x32_bf16(al[rt], bh, tacc[rt][ct], 0, 0, 0);
          }
        }
      }
      __syncthreads();   // all h reads done
      #pragma unroll
      for (int rt = 0; rt < 2; ++rt) {
        int row0 = rg*32 + rt*16 + (lane >> 4)*4;
        #pragma unroll
        for (int ct = 0; ct < 4; ++ct) {
          int c = cg*64 + ct*16 + lr;
          #pragma unroll
          for (int j = 0; j < 4; ++j) tbuf[(row0+j)*TSTR + c] = tacc[rt][ct][j];
        }
      }
      __syncthreads();   // T ready
    }

    // ---- aggregation (f32, sparse) ----
    int v = tid >> 2, fq = tid & 3;
    int cb = fq * 4;
    float4 acc[8] = {};
    {
      float dv = dinv[v];
      if (dv > 0.f) {
        int e0 = rloc[v], e1 = rloc[v+1];
        for (int e = e0; e < e1; ++e) {
          int s = colS[e];
          float w = dinv[s];
          if (w > 0.f) {
            const float* ts = &tbuf[s*TSTR + cb];
            #pragma unroll
            for (int i = 0; i < 8; ++i) {
              float4 tv = *(const float4*)&ts[i*16];
              acc[i].x += w*tv.x; acc[i].y += w*tv.y;
              acc[i].z += w*tv.z; acc[i].w += w*tv.w;
            }
          }
        }
        const float* tv0 = &tbuf[v*TSTR + cb];
        #pragma unroll
        for (int i = 0; i < 8; ++i) {
          float4 tv = *(const float4*)&tv0[i*16];
          acc[i].x += dv*tv.x; acc[i].y += dv*tv.y;
          acc[i].z += dv*tv.z; acc[i].w += dv*tv.w;
        }
        #pragma unroll
        for (int i = 0; i < 8; ++i) {
          acc[i].x *= dv; acc[i].y *= dv; acc[i].z *= dv; acc[i].w *= dv;
        }
      }
    }
    __syncthreads();   // all T reads done
    #pragma unroll
    for (int i = 0; i < 8; ++i) {
      int ci = i*16 + cb;
      float4 a = acc[i];
      a.x = fmaxf(a.x + bvec[ci+0], 0.f);
      a.y = fmaxf(a.y + bvec[ci+1], 0.f);
      a.z = fmaxf(a.z + bvec[ci+2], 0.f);
      a.w = fmaxf(a.w + bvec[ci+3], 0.f);
      *(float4*)&tbuf[v*TSTR + ci] = a;
    }
    __syncthreads();   // h ready

    // ---- score pre-transform: tsv[v] = h[v] . Ws ----
    {
      for (int j = 0; j < 16; ++j) {
        int vv = wid*16 + j;
        float p = tbuf[vv*TSTR + lane]*wsv[lane] + tbuf[vv*TSTR + 64 + lane]*wsv[64+lane];
        #pragma unroll
        for (int o = 32; o > 0; o >>= 1) p += __shfl_xor(p, o);
        if (lane == 0) tsv[vv] = p;
      }
    }
    __syncthreads();

    // ---- score aggregation ----
    if (tid < NPG) {
      float dv = dinv[tid];
      float sa = 0.f;
      if (dv > 0.f) {
        int e0 = rloc[tid], e1 = rloc[tid+1];
        for (int e = e0; e < e1; ++e) { int s = colS[e]; sa += tsv[s]*dinv[s]; }
        sa = dv*(sa + dv*tsv[tid]);
      }
      score[tid] = sa + bscp[0];
      nmf[tid] = 0.f;
    }
    __syncthreads();

    // ---- register bitonic top-K (4 waves), desc score / asc idx ----
    float kf = -INFINITY; int ki = tid;
    if (tid < NPG) {
      kf = (mprev[tid] > 0.f) ? score[tid] : -INFINITY;
      for (int kk = 2; kk <= 64; kk <<= 1)
        for (int j = kk >> 1; j > 0; j >>= 1) {
          float ok = __shfl_xor(kf, j);
          int   oi = __shfl_xor(ki, j);
          BSTEP(ok, oi, kk, j);
        }
    }
    if (tid < NPG) { skey[tid] = kf; sidx[tid] = ki; }
    __syncthreads();
    if (tid < NPG) {
      int l = tid ^ 64; float ok = skey[l]; int oi = sidx[l];
      BSTEP(ok, oi, 128, 64);
      for (int j = 32; j > 0; j >>= 1) {
        float sk = __shfl_xor(kf, j); int si = __shfl_xor(ki, j);
        BSTEP(sk, si, 128, j);
      }
    }
    __syncthreads();
    if (tid < NPG) { skey[tid] = kf; sidx[tid] = ki; }
    __syncthreads();
    if (tid < NPG) {
      int l = tid ^ 128; float ok = skey[l]; int oi = sidx[l];
      BSTEP(ok, oi, 256, 128);
    }
    __syncthreads();
    if (tid < NPG) { skey[tid] = kf; sidx[tid] = ki; }
    __syncthreads();
    if (tid < NPG) {
      int l = tid ^ 64; float ok = skey[l]; int oi = sidx[l];
      BSTEP(ok, oi, 256, 64);
      for (int j = 32; j > 0; j >>= 1) {
        float sk = __shfl_xor(kf, j); int si = __shfl_xor(ki, j);
        BSTEP(sk, si, 256, j);
      }
    }
    if (tid < K) nmf[ki] = 1.0f;
    __syncthreads();

    if (tid < NPG) {
      tscale[tid] = tanhf(score[tid]) * nmf[tid];
      mprev[tid] = nmf[tid];
    }
    __syncthreads();

    // ---- scale features in place ----
    {
      float tsc = tscale[v];
      #pragma unroll
      for (int i = 0; i < 8; ++i) {
        int ci = i*16 + cb;
        float4 t = *(float4*)&tbuf[v*TSTR + ci];
        t.x *= tsc; t.y *= tsc; t.z *= tsc; t.w *= tsc;
        *(float4*)&tbuf[v*TSTR + ci] = t;
      }
    }
    __syncthreads();

    // ---- readout: max & mean over selected nodes -> zacc ----
    {
      int f = tid & 127, vg = tid >> 7;
      float mx = -INFINITY, sm = 0.f;
      for (int vr = 0; vr < 32; ++vr) {
        int vv = vg*32 + vr;
        float val = tbuf[vv*TSTR + f];
        if (nmf[vv] > 0.f) { mx = fmaxf(mx, val); sm += val; }
      }
      red[vg*HF + f] = mx;
      __syncthreads();
      if (tid < HF) {
        float zm = red[tid];
        #pragma unroll
        for (int q = 1; q < 8; ++q) zm = fmaxf(zm, red[q*HF + tid]);
        if (first) zacc[tid] = zm; else zacc[tid] += zm;
      }
      __syncthreads();
      red[vg*HF + f] = sm;
      __syncthreads();
      if (tid < HF) {
        float zs = red[tid];
        #pragma unroll
        for (int q = 1; q < 8; ++q) zs += red[q*HF + tid];
        float mn = zs / (float)K;
        if (first) zacc[HF + tid] = mn; else zacc[HF + tid] += mn;
      }
      __syncthreads();
    }
  }

  // ---- MLP head + log_softmax ----
  {
    int o = tid & 127, kg = tid >> 7;
    float p = 0.f;
    int k0 = kg*32;
    for (int k = k0; k < k0+32; ++k) p += zacc[k]*Wl1[k*HF + o];
    red[kg*HF + o] = p;
    __syncthreads();
    if (tid < HF) {
      float a = bl1[tid];
      #pragma unroll
      for (int q = 0; q < 8; ++q) a += red[q*HF + tid];
      score[tid] = fmaxf(a, 0.f);       // h1
    }
    __syncthreads();
    if (tid < 512) {
      int o2 = tid & 63, kg2 = tid >> 6;
      float p2 = 0.f;
      int k0b = kg2*16;
      for (int k = k0b; k < k0b+16; ++k) p2 += score[k]*Wl2[k*64 + o2];
      red[kg2*64 + o2] = p2;
    }
    __syncthreads();
    if (tid < 64) {
      float a = bl2[tid];
      #pragma unroll
      for (int q = 0; q < 8; ++q) a += red[q*64 + tid];
      tscale[tid] = fmaxf(a, 0.f);      // h2
    }
    __syncthreads();
    if (tid < 10) {
      float a = bl3[tid];
      for (int k = 0; k < 64; ++k) a += tscale[k]*Wl3[k*10 + tid];
      nmf[tid] = fmaxf(a, 0.f);         // logits
    }
    __syncthreads();
    if (tid == 0) {
      float m = nmf[0];
      for (int i = 1; i < 10; ++i) m = fmaxf(m, nmf[i]);
      float s = 0.f;
      for (int i = 0; i < 10; ++i) s += expf(nmf[i] - m);
      red[0] = m; red[1] = logf(s);
    }
    __syncthreads();
    if (tid < 10) out[(size_t)g*10 + tid] = nmf[tid] - red[0] - red[1];
  }
}

extern "C" void kernel_launch(void* const* d_in, const int* in_sizes, int n_in,
                              void* d_out, int out_size, void* d_ws, size_t ws_size,
                              hipStream_t stream) {
  const float* x   = (const float*)d_in[0];
  const int*  srcI = (const int*)d_in[1];
  const int*  dstI = (const int*)d_in[2];
  const float* W1  = (const float*)d_in[3];
  const float* b1  = (const float*)d_in[4];
  const float* W2  = (const float*)d_in[5];
  const float* b2  = (const float*)d_in[6];
  const float* W3  = (const float*)d_in[7];
  const float* b3  = (const float*)d_in[8];
  const float* Ws1 = (const float*)d_in[9];
  const float* bs1 = (const float*)d_in[10];
  const float* Ws2 = (const float*)d_in[11];
  const float* bs2 = (const float*)d_in[12];
  const float* Ws3 = (const float*)d_in[13];
  const float* bs3 = (const float*)d_in[14];
  const float* Wl1 = (const float*)d_in[15];
  const float* bl1 = (const float*)d_in[16];
  const float* Wl2 = (const float*)d_in[17];
  const float* bl2 = (const float*)d_in[18];
  const float* Wl3 = (const float*)d_in[19];
  const float* bl3 = (const float*)d_in[20];
  float* out = (float*)d_out;

  short* WtAll = (short*)d_ws;   // 3 * 2 * 16384 shorts = 192 KB

  prep_wt<<<192, 256, 0, stream>>>(W1, W2, W3, WtAll);
  fused_net<<<NGRAPH, 1024, 0, stream>>>(x, srcI, dstI, WtAll,
                                         b1, Ws1, bs1, b2, Ws2, bs2, b3, Ws3, bs3,
                                         Wl1, bl1, Wl2, bl2, Wl3, bl3, out);
}

// Round 4
// 133.869 us; speedup vs baseline: 1.9928x; 1.1716x over previous
//
#include <hip/hip_runtime.h>
#include <math.h>

#define NGRAPH 256
#define NPG 256
#define HF 128
#define EPG 4096
#define FSTR 132      // f32 row stride in tbufF (aliases hpair)
#define PSTR 136      // short row stride in hpair (16B-aligned rows, staggered banks)

typedef __attribute__((ext_vector_type(8))) short bf16x8;
typedef __attribute__((ext_vector_type(4))) float f32x4;

static __device__ __forceinline__ unsigned bcu(float f){ return __builtin_bit_cast(unsigned, f); }
static __device__ __forceinline__ float bcf(unsigned u){ return __builtin_bit_cast(float, u); }
static __device__ __forceinline__ unsigned rtn16(float f){
  unsigned u = bcu(f);
  return (u + 0x7FFFu + ((u >> 16) & 1u)) >> 16;
}

// ---------------- W transpose + split to bf16 hi/lo: Wt[n][k] ----------------
__global__ __launch_bounds__(256) void prep_wt(const float* __restrict__ W1,
                                               const float* __restrict__ W2,
                                               const float* __restrict__ W3,
                                               short* __restrict__ Wt) {
  int idx = blockIdx.x * 256 + threadIdx.x;           // 0 .. 3*16384
  int L = idx >> 14, r = idx & 16383;
  int k = r >> 7, n = r & 127;
  const float* W = (L == 0) ? W1 : (L == 1) ? W2 : W3;
  float w = W[k*128 + n];
  unsigned hi = rtn16(w);
  float lo = w - bcf(hi << 16);
  short* Whi = Wt + (size_t)L * 2 * 16384;
  short* Wlo = Whi + 16384;
  Whi[n*128 + k] = (short)hi;
  Wlo[n*128 + k] = (short)(bcu(lo) >> 16);
}

// sort compare-exchange step (descending key, ascending idx on ties)
#define BSTEP(OK, OI, KKc, Jc) do { \
  bool iLess = ((tid & (Jc)) == 0); \
  bool descR = ((tid & (KKc)) == 0); \
  bool myFirst = (kf > (OK)) || (kf == (OK) && ki < (OI)); \
  bool keep = (iLess == descR) ? myFirst : !myFirst; \
  if (!keep) { kf = (OK); ki = (OI); } \
} while (0)

// ---------------- whole network, one block per graph ----------------
__global__ __launch_bounds__(1024) void fused_net(
    const float* __restrict__ x,
    const int* __restrict__ srcI, const int* __restrict__ dstI,
    const short* __restrict__ WtAll,
    const float* __restrict__ b1, const float* __restrict__ Ws1, const float* __restrict__ bs1,
    const float* __restrict__ b2, const float* __restrict__ Ws2, const float* __restrict__ bs2,
    const float* __restrict__ b3, const float* __restrict__ Ws3, const float* __restrict__ bs3,
    const float* __restrict__ Wl1, const float* __restrict__ bl1,
    const float* __restrict__ Wl2, const float* __restrict__ bl2,
    const float* __restrict__ Wl3, const float* __restrict__ bl3,
    float* __restrict__ out)
{
  __shared__ __align__(16) short hpair[2][NPG*PSTR];   // 139264 B; aliased by tbufF
  __shared__ unsigned char colS[EPG];                  // CSR col (src local idx), by dst
  __shared__ unsigned short rloc[NPG+2];
  __shared__ unsigned mbits[8];                        // survivor bitmask
  __shared__ float dinv[NPG];
  __shared__ __align__(16) float bvec[HF];
  __shared__ __align__(16) float wsv[HF];
  __shared__ float tsv[NPG];
  __shared__ float score[NPG];
  __shared__ float tscale[NPG];                        // doubles as tq scratch
  __shared__ float nmf[NPG];
  __shared__ float skey[NPG];
  __shared__ int   sidx[NPG];
  __shared__ __align__(16) float red[1024];            // tsv partials / readout / MLP scratch
  __shared__ float zacc[2*HF];

  float* tbufF = (float*)&hpair[0][0];                 // [node][FSTR] f32, alias
  short* hp0 = &hpair[0][0];
  short* hp1 = &hpair[1][0];
  int* cntA = (int*)skey;                              // CSR-build-only aliases
  int* curA = sidx;

  int tid = threadIdx.x;
  int g = blockIdx.x;
  size_t nbase = (size_t)g * NPG;
  int lane = tid & 63, wid = tid >> 6;
  int v = tid >> 2, fq = tid & 3, cb = fq * 4;

  // ---- stage x into bf16 hi/lo pair ----
  const float4* X4 = (const float4*)(x + nbase*HF);
  #pragma unroll
  for (int i = 0; i < 8; ++i) {
    int f4 = tid + i*1024;
    int r = f4 >> 5, kq = f4 & 31;
    float4 val = X4[f4];
    unsigned rx = rtn16(val.x), ry = rtn16(val.y), rz = rtn16(val.z), rw = rtn16(val.w);
    uint2 ph; ph.x = rx | (ry << 16); ph.y = rz | (rw << 16);
    float lx = val.x - bcf(rx << 16), ly = val.y - bcf(ry << 16);
    float lz = val.z - bcf(rz << 16), lw = val.w - bcf(rw << 16);
    uint2 pl; pl.x = (bcu(lx) >> 16) | (bcu(ly) & 0xFFFF0000u);
    pl.y = (bcu(lz) >> 16) | (bcu(lw) & 0xFFFF0000u);
    *(uint2*)&hp0[r*PSTR + kq*4] = ph;
    *(uint2*)&hp1[r*PSTR + kq*4] = pl;
  }

  // ---- CSR build in LDS ----
  if (tid < NPG) cntA[tid] = 0;
  if (tid < 8) mbits[tid] = 0xFFFFFFFFu;
  __syncthreads();
  int nb = g * NPG;
  int dloc[4], sloc[4];
  #pragma unroll
  for (int it = 0; it < 4; ++it) {
    int e = g*EPG + tid + it*1024;
    dloc[it] = dstI[e] - nb;
    sloc[it] = srcI[e] - nb;
    atomicAdd(&cntA[dloc[it]], 1);
  }
  __syncthreads();
  if (tid < NPG) sidx[tid] = cntA[tid];
  __syncthreads();
  for (int off = 1; off < NPG; off <<= 1) {
    int t = (tid >= off && tid < NPG) ? sidx[tid-off] : 0;
    __syncthreads();
    if (tid < NPG) sidx[tid] += t;
    __syncthreads();
  }
  int excl_ = 0;
  if (tid < NPG) excl_ = sidx[tid] - cntA[tid];
  __syncthreads();
  if (tid < NPG) { rloc[tid] = (unsigned short)excl_; curA[tid] = excl_; }
  if (tid == 0) rloc[NPG] = (unsigned short)EPG;
  __syncthreads();
  #pragma unroll
  for (int it = 0; it < 4; ++it) {
    int slot = atomicAdd(&curA[dloc[it]], 1);
    colS[slot] = (unsigned char)sloc[it];
  }

  // ---- 3 GCN+SAGPool layers ----
  #pragma unroll 1
  for (int L = 0; L < 3; ++L) {
    const short* Whi = WtAll + (size_t)L * 2 * 16384;
    const short* Wlo = Whi + 16384;
    const float* bias = (L == 0) ? b1 : (L == 1) ? b2 : b3;
    const float* Wsc  = (L == 0) ? Ws1 : (L == 1) ? Ws2 : Ws3;
    const float* bscp = (L == 0) ? bs1 : (L == 1) ? bs2 : bs3;
    int K = NPG >> (L + 1);          // 128, 64, 32

    __syncthreads();   // B0: pair writes (or stage/CSR) complete

    // ---- params + dinv (concurrent with transform reads; disjoint data) ----
    if (tid < HF) { bvec[tid] = bias[tid]; wsv[tid] = Wsc[tid]; }
    if (tid < NPG) {
      unsigned mb[8];
      #pragma unroll
      for (int j = 0; j < 8; ++j) mb[j] = mbits[j];
      int e0 = rloc[tid], e1 = rloc[tid+1];
      int c = 0;
      for (int e = e0; e < e1; ++e) {
        int s = colS[e];
        c += (mb[s>>5] >> (s&31)) & 1;
      }
      bool alive = (mb[tid>>5] >> (tid&31)) & 1;
      dinv[tid] = alive ? (1.0f / sqrtf((float)c + 1.0f)) : 0.0f;
    }

    // ---- transform T = h @ W (MFMA on resident bf16 pair, in place) ----
    {
      int rg = wid & 7, cg = wid >> 3;
      int lr = lane & 15, lk8 = (lane >> 4) * 8;
      f32x4 tacc[2][4] = {};
      #pragma unroll
      for (int kc = 0; kc < 4; ++kc) {
        int k0 = kc*32 + lk8;
        bf16x8 ah[2], al[2];
        #pragma unroll
        for (int rt = 0; rt < 2; ++rt) {
          int row = rg*32 + rt*16 + lr;
          ah[rt] = *(const bf16x8*)&hp0[row*PSTR + k0];
          al[rt] = *(const bf16x8*)&hp1[row*PSTR + k0];
        }
        #pragma unroll
        for (int ct = 0; ct < 4; ++ct) {
          int n = cg*64 + ct*16 + lr;
          bf16x8 bh = *(const bf16x8*)&Whi[n*HF + k0];
          bf16x8 bl = *(const bf16x8*)&Wlo[n*HF + k0];
          #pragma unroll
          for (int rt = 0; rt < 2; ++rt) {
            tacc[rt][ct] = __builtin_amdgcn_mfma_f32_16x16x32_bf16(ah[rt], bh, tacc[rt][ct], 0, 0, 0);
            tacc[rt][ct] = __builtin_amdgcn_mfma_f32_16x16x32_bf16(al[rt], bh, tacc[rt][ct], 0, 0, 0);
            tacc[rt][ct] = __builtin_amdgcn_mfma_f32_16x16x32_bf16(ah[rt], bl, tacc[rt][ct], 0, 0, 0);
          }
        }
      }
      __syncthreads();   // B1: all pair reads done
      #pragma unroll
      for (int rt = 0; rt < 2; ++rt) {
        int row0 = rg*32 + rt*16 + (lane >> 4)*4;
        #pragma unroll
        for (int ct = 0; ct < 4; ++ct) {
          int c = cg*64 + ct*16 + (lane & 15);
          #pragma unroll
          for (int j = 0; j < 4; ++j) tbufF[(row0+j)*FSTR + c] = tacc[rt][ct][j];
        }
      }
    }
    __syncthreads();   // B2: T ready

    // ---- aggregation (f32 gather) + relu + fused score partial ----
    float4 hv[8];
    {
      float dv = dinv[v];
      float4 acc[8] = {};
      if (dv > 0.f) {
        int e0 = rloc[v], e1 = rloc[v+1];
        for (int e = e0; e < e1; ++e) {
          int s = colS[e];
          float w = dinv[s];
          const float* ts = &tbufF[s*FSTR + cb];
          #pragma unroll
          for (int i = 0; i < 8; ++i) {
            float4 tv = *(const float4*)&ts[i*16];
            acc[i].x += w*tv.x; acc[i].y += w*tv.y;
            acc[i].z += w*tv.z; acc[i].w += w*tv.w;
          }
        }
        const float* tv0 = &tbufF[v*FSTR + cb];
        #pragma unroll
        for (int i = 0; i < 8; ++i) {
          float4 tv = *(const float4*)&tv0[i*16];
          acc[i].x = dv*(acc[i].x + dv*tv.x);
          acc[i].y = dv*(acc[i].y + dv*tv.y);
          acc[i].z = dv*(acc[i].z + dv*tv.z);
          acc[i].w = dv*(acc[i].w + dv*tv.w);
        }
      }
      float p = 0.f;
      #pragma unroll
      for (int i = 0; i < 8; ++i) {
        int ci = i*16 + cb;
        float4 bv = *(const float4*)&bvec[ci];
        float4 wv = *(const float4*)&wsv[ci];
        float4 a = acc[i];
        a.x = fmaxf(a.x + bv.x, 0.f);
        a.y = fmaxf(a.y + bv.y, 0.f);
        a.z = fmaxf(a.z + bv.z, 0.f);
        a.w = fmaxf(a.w + bv.w, 0.f);
        hv[i] = a;
        p += a.x*wv.x + a.y*wv.y + a.z*wv.z + a.w*wv.w;
      }
      red[tid] = p;
    }
    __syncthreads();   // B3: score partials ready, T gathers done
    if (tid < NPG) {
      float4 q = *(const float4*)&red[tid*4];
      float s4 = (q.x + q.y) + (q.z + q.w);
      tsv[tid] = s4;
      tscale[tid] = s4 * dinv[tid];    // tq
      nmf[tid] = 0.f;
    }
    __syncthreads();   // B4
    if (tid < NPG) {
      float dv = dinv[tid];
      float sa = 0.f;
      if (dv > 0.f) {
        int e0 = rloc[tid], e1 = rloc[tid+1];
        for (int e = e0; e < e1; ++e) sa += tscale[colS[e]];
        sa = dv*(sa + dv*tsv[tid]);
      }
      score[tid] = sa + bscp[0];
    }
    __syncthreads();   // B5: scores ready

    // ---- register bitonic top-K (4 waves), desc score / asc idx ----
    float kf = -INFINITY; int ki = tid;
    if (tid < NPG) {
      bool alive = (mbits[tid>>5] >> (tid&31)) & 1;
      kf = alive ? score[tid] : -INFINITY;
      for (int kk = 2; kk <= 64; kk <<= 1)
        for (int j = kk >> 1; j > 0; j >>= 1) {
          float ok = __shfl_xor(kf, j);
          int   oi = __shfl_xor(ki, j);
          BSTEP(ok, oi, kk, j);
        }
    }
    if (tid < NPG) { skey[tid] = kf; sidx[tid] = ki; }
    __syncthreads();
    if (tid < NPG) {
      int l = tid ^ 64; float ok = skey[l]; int oi = sidx[l];
      BSTEP(ok, oi, 128, 64);
      for (int j = 32; j > 0; j >>= 1) {
        float sk = __shfl_xor(kf, j); int si = __shfl_xor(ki, j);
        BSTEP(sk, si, 128, j);
      }
    }
    __syncthreads();
    if (tid < NPG) { skey[tid] = kf; sidx[tid] = ki; }
    __syncthreads();
    if (tid < NPG) {
      int l = tid ^ 128; float ok = skey[l]; int oi = sidx[l];
      BSTEP(ok, oi, 256, 128);
    }
    __syncthreads();
    if (tid < NPG) { skey[tid] = kf; sidx[tid] = ki; }
    __syncthreads();
    if (tid < NPG) {
      int l = tid ^ 64; float ok = skey[l]; int oi = sidx[l];
      BSTEP(ok, oi, 256, 64);
      for (int j = 32; j > 0; j >>= 1) {
        float sk = __shfl_xor(kf, j); int si = __shfl_xor(ki, j);
        BSTEP(sk, si, 256, j);
      }
    }
    __syncthreads();
    if (tid < 8) mbits[tid] = 0u;
    __syncthreads();
    if (tid < K) { nmf[ki] = 1.0f; atomicOr(&mbits[ki>>5], 1u << (ki&31)); }
    __syncthreads();
    if (tid < NPG) tscale[tid] = tanhf(score[tid]) * nmf[tid];
    __syncthreads();

    // ---- scale (regs) + write f32 for readout ----
    {
      float ts = tscale[v];
      #pragma unroll
      for (int i = 0; i < 8; ++i) {
        hv[i].x *= ts; hv[i].y *= ts; hv[i].z *= ts; hv[i].w *= ts;
        *(float4*)&tbufF[v*FSTR + i*16 + cb] = hv[i];
      }
    }
    __syncthreads();

    // ---- readout: max & mean over selected nodes -> zacc ----
    {
      int f = tid & 127, vg = tid >> 7;
      float mx = -INFINITY, sm = 0.f;
      for (int vr = 0; vr < 32; ++vr) {
        int vv = vg*32 + vr;
        float val = tbufF[vv*FSTR + f];
        if (nmf[vv] > 0.f) { mx = fmaxf(mx, val); sm += val; }
      }
      red[vg*HF + f] = mx;
      __syncthreads();
      if (tid < HF) {
        float zm = red[tid];
        #pragma unroll
        for (int q = 1; q < 8; ++q) zm = fmaxf(zm, red[q*HF + tid]);
        if (L == 0) zacc[tid] = zm; else zacc[tid] += zm;
      }
      __syncthreads();
      red[vg*HF + f] = sm;
      __syncthreads();
      if (tid < HF) {
        float zs = red[tid];
        #pragma unroll
        for (int q = 1; q < 8; ++q) zs += red[q*HF + tid];
        float mn = zs / (float)K;
        if (L == 0) zacc[HF + tid] = mn; else zacc[HF + tid] += mn;
      }
      __syncthreads();   // also: all tbufF/red reads done
    }

    // ---- pack scaled h into bf16 pair for next layer ----
    if (L < 2) {
      #pragma unroll
      for (int i = 0; i < 8; ++i) {
        int ci = i*16 + cb;
        float4 val = hv[i];
        unsigned rx = rtn16(val.x), ry = rtn16(val.y), rz = rtn16(val.z), rw = rtn16(val.w);
        uint2 ph; ph.x = rx | (ry << 16); ph.y = rz | (rw << 16);
        float lx = val.x - bcf(rx << 16), ly = val.y - bcf(ry << 16);
        float lz = val.z - bcf(rz << 16), lw = val.w - bcf(rw << 16);
        uint2 pl; pl.x = (bcu(lx) >> 16) | (bcu(ly) & 0xFFFF0000u);
        pl.y = (bcu(lz) >> 16) | (bcu(lw) & 0xFFFF0000u);
        *(uint2*)&hp0[v*PSTR + ci] = ph;
        *(uint2*)&hp1[v*PSTR + ci] = pl;
      }
    }
  }

  __syncthreads();

  // ---- MLP head + log_softmax ----
  {
    int o = tid & 127, kg = tid >> 7;
    float p = 0.f;
    int k0 = kg*32;
    for (int k = k0; k < k0+32; ++k) p += zacc[k]*Wl1[k*HF + o];
    red[kg*HF + o] = p;
    __syncthreads();
    if (tid < HF) {
      float a = bl1[tid];
      #pragma unroll
      for (int q = 0; q < 8; ++q) a += red[q*HF + tid];
      score[tid] = fmaxf(a, 0.f);       // h1
    }
    __syncthreads();
    if (tid < 512) {
      int o2 = tid & 63, kg2 = tid >> 6;
      float p2 = 0.f;
      int k0b = kg2*16;
      for (int k = k0b; k < k0b+16; ++k) p2 += score[k]*Wl2[k*64 + o2];
      red[kg2*64 + o2] = p2;
    }
    __syncthreads();
    if (tid < 64) {
      float a = bl2[tid];
      #pragma unroll
      for (int q = 0; q < 8; ++q) a += red[q*64 + tid];
      tscale[tid] = fmaxf(a, 0.f);      // h2
    }
    __syncthreads();
    if (tid < 10) {
      float a = bl3[tid];
      for (int k = 0; k < 64; ++k) a += tscale[k]*Wl3[k*10 + tid];
      nmf[tid] = fmaxf(a, 0.f);         // logits
    }
    __syncthreads();
    if (tid == 0) {
      float m = nmf[0];
      for (int i = 1; i < 10; ++i) m = fmaxf(m, nmf[i]);
      float s = 0.f;
      for (int i = 0; i < 10; ++i) s += expf(nmf[i] - m);
      red[0] = m; red[1] = logf(s);
    }
    __syncthreads();
    if (tid < 10) out[(size_t)g*10 + tid] = nmf[tid] - red[0] - red[1];
  }
}

extern "C" void kernel_launch(void* const* d_in, const int* in_sizes, int n_in,
                              void* d_out, int out_size, void* d_ws, size_t ws_size,
                              hipStream_t stream) {
  const float* x   = (const float*)d_in[0];
  const int*  srcI = (const int*)d_in[1];
  const int*  dstI = (const int*)d_in[2];
  const float* W1  = (const float*)d_in[3];
  const float* b1  = (const float*)d_in[4];
  const float* W2  = (const float*)d_in[5];
  const float* b2  = (const float*)d_in[6];
  const float* W3  = (const float*)d_in[7];
  const float* b3  = (const float*)d_in[8];
  const float* Ws1 = (const float*)d_in[9];
  const float* bs1 = (const float*)d_in[10];
  const float* Ws2 = (const float*)d_in[11];
  const float* bs2 = (const float*)d_in[12];
  const float* Ws3 = (const float*)d_in[13];
  const float* bs3 = (const float*)d_in[14];
  const float* Wl1 = (const float*)d_in[15];
  const float* bl1 = (const float*)d_in[16];
  const float* Wl2 = (const float*)d_in[17];
  const float* bl2 = (const float*)d_in[18];
  const float* Wl3 = (const float*)d_in[19];
  const float* bl3 = (const float*)d_in[20];
  float* out = (float*)d_out;

  short* WtAll = (short*)d_ws;   // 3 * 2 * 16384 shorts = 192 KB

  prep_wt<<<192, 256, 0, stream>>>(W1, W2, W3, WtAll);
  fused_net<<<NGRAPH, 1024, 0, stream>>>(x, srcI, dstI, WtAll,
                                         b1, Ws1, bs1, b2, Ws2, bs2, b3, Ws3, bs3,
                                         Wl1, bl1, Wl2, bl2, Wl3, bl3, out);
}